// Round 6
// baseline (289.971 us; speedup 1.0000x reference)
//
#include <hip/hip_runtime.h>
#include <hip/hip_fp16.h>

#define LDIM 2048
#define DDIM 1024
#define NB 8

typedef __attribute__((ext_vector_type(8))) _Float16 f16x8;
typedef __attribute__((ext_vector_type(4))) float f32x4;
typedef unsigned int u32;

#define MFMA16(a, b, c) __builtin_amdgcn_mfma_f32_16x16x32_f16(a, b, c, 0, 0, 0)

typedef const __attribute__((address_space(1))) u32* gas_t;
typedef __attribute__((address_space(3))) u32* las_t;

__device__ __forceinline__ void gl16(const _Float16* g, _Float16* l) {
  __builtin_amdgcn_global_load_lds((gas_t)g, (las_t)l, 16, 0, 0);
}

#define SBAR() __builtin_amdgcn_s_barrier()
#define VMCNT(n) asm volatile("s_waitcnt vmcnt(" #n ")" ::: "memory")
#define LGKM0 asm volatile("s_waitcnt lgkmcnt(0)" ::: "memory")
#define SCHED0 __builtin_amdgcn_sched_barrier(0)

// ---------------------------------------------------------------------------
// 256x256 GEMM core, BK=64, 8 waves (2M x 4N), wave tile 128x64.
// LDS (halves): region(buf,op,mh,kh) = buf*32768 + op*16384 + mh*8192 + kh*4096;
// within region: row(0..127)*32 + chunk*8, source-chunk pre-swizzled by
// (row>>1)&3 (involution; measured conflict-free in R3-R5).
// Phase (MH,KS,BUF): [bf reads if MH==0; af reads; sched_barrier; stage
// half-tile; counted vmcnt; s_barrier; lgkmcnt(0); sched_barrier; setprio(1);
// 16 MFMA; setprio(0); s_barrier].  B-frags reused across the two MH phases.
// ---------------------------------------------------------------------------
template <int MH, int KS, int BUF, bool RB, class FS, class FW>
__device__ __forceinline__ void ph(const _Float16* sh, int base_a, int base_b,
                                   f16x8 (&bf)[4], f32x4 (&acc)[2][4][4], FS stg, FW wt) {
  f16x8 af[4];
  if (RB) {
#pragma unroll
    for (int nr = 0; nr < 4; ++nr)
      bf[nr] = *(const f16x8*)&sh[BUF * 32768 + KS * 4096 + base_b + nr * 512];
  }
#pragma unroll
  for (int mr = 0; mr < 4; ++mr)
    af[mr] = *(const f16x8*)&sh[BUF * 32768 + KS * 4096 + MH * 2048 + base_a + mr * 512];
  SCHED0;            // pin ds_reads BEFORE the barrier (prevent sinking)
  stg();
  wt();
  __builtin_amdgcn_s_barrier();
  LGKM0;
  SCHED0;            // rule 18: keep MFMA below the lgkm wait
  __builtin_amdgcn_s_setprio(1);
#pragma unroll
  for (int mr = 0; mr < 4; ++mr)
#pragma unroll
    for (int nr = 0; nr < 4; ++nr)
      acc[MH][mr][nr] = MFMA16(af[mr], bf[nr], acc[MH][mr][nr]);
  __builtin_amdgcn_s_setprio(0);
  SCHED0;
  __builtin_amdgcn_s_barrier();
}

template <int LDA, int NT>
__device__ __forceinline__ void gemm8(const _Float16* __restrict__ Ab,
                                      const _Float16* __restrict__ Bb,
                                      _Float16* sh, f32x4 (&acc)[2][4][4]) {
  const int tid = threadIdx.x;
  const int lane = tid & 63, w = tid >> 6;
  const int wm = w >> 2, wn = w & 3;
  const int l15 = lane & 15, g4 = lane >> 4;

  const int chk = (g4 ^ ((l15 >> 1) & 3)) << 3;
  const int base_a = wm * 8192 + l15 * 32 + chk;                               // A op
  const int base_b = 16384 + (wn >> 1) * 8192 + ((wn & 1) * 64 + l15) * 32 + chk;  // B op

  const int srow = tid >> 2;                       // staging row 0..127
  const int scg = (tid & 3) ^ ((srow >> 1) & 3);   // pre-swizzled source chunk
  const _Float16* gA = Ab + (size_t)srow * LDA + scg * 8;
  const _Float16* gB = Bb + (size_t)srow * LDA + scg * 8;
  _Float16* lw = sh + w * 512;  // wave-uniform LDS base (HW adds lane*16B)

  // stage half-tile (op, kh) of tile T: 2 x gload_lds covering mh0, mh1
  auto stg = [&](int T, int op, int kh) {
    const _Float16* g = (op ? gB : gA) + (size_t)T * 64 + kh * 32;
    _Float16* l = lw + (T & 1) * 32768 + op * 16384 + kh * 4096;
    gl16(g, l);
    gl16(g + (size_t)128 * LDA, l + 8192);
  };

  f16x8 bf[4];

  // prologue: T0 all 4 half-tiles, T1 first 3; confirm T0 (14 issued, wait to 6)
  stg(0, 1, 0); stg(0, 0, 0); stg(0, 1, 1); stg(0, 0, 1);
  stg(1, 1, 0); stg(1, 0, 0); stg(1, 1, 1);
  VMCNT(6);
  SBAR();

  for (int i = 0; i < NT / 2 - 1; ++i) {
    const int T1 = 2 * i + 1, T2 = 2 * i + 2, T3 = 2 * i + 3;
    ph<0, 0, 0, true >(sh, base_a, base_b, bf, acc, [&] { stg(T1, 0, 1); }, [] {});
    ph<1, 0, 0, false>(sh, base_a, base_b, bf, acc, [&] { stg(T2, 1, 0); }, [] {});
    ph<0, 1, 0, true >(sh, base_a, base_b, bf, acc, [&] { stg(T2, 0, 0); }, [] {});
    ph<1, 1, 0, false>(sh, base_a, base_b, bf, acc, [&] { stg(T2, 1, 1); }, [] { VMCNT(6); });
    ph<0, 0, 1, true >(sh, base_a, base_b, bf, acc, [&] { stg(T2, 0, 1); }, [] {});
    ph<1, 0, 1, false>(sh, base_a, base_b, bf, acc, [&] { stg(T3, 1, 0); }, [] {});
    ph<0, 1, 1, true >(sh, base_a, base_b, bf, acc, [&] { stg(T3, 0, 0); }, [] {});
    ph<1, 1, 1, false>(sh, base_a, base_b, bf, acc, [&] { stg(T3, 1, 1); }, [] { VMCNT(6); });
  }
  {  // tail: T0=NT-2 (buf0), T1=NT-1 (buf1)
    ph<0, 0, 0, true >(sh, base_a, base_b, bf, acc, [&] { stg(NT - 1, 0, 1); }, [] {});
    ph<1, 0, 0, false>(sh, base_a, base_b, bf, acc, [] {}, [] {});
    ph<0, 1, 0, true >(sh, base_a, base_b, bf, acc, [] {}, [] {});
    ph<1, 1, 0, false>(sh, base_a, base_b, bf, acc, [] {}, [] { VMCNT(0); });
    ph<0, 0, 1, true >(sh, base_a, base_b, bf, acc, [] {}, [] {});
    ph<1, 0, 1, false>(sh, base_a, base_b, bf, acc, [] {}, [] {});
    ph<0, 1, 1, true >(sh, base_a, base_b, bf, acc, [] {}, [] {});
    ph<1, 1, 1, false>(sh, base_a, base_b, bf, acc, [] {}, [] {});
  }
}

// ---------------------------------------------------------------------------
// k_prep: F (fp32 [2048][1024]) -> H (fp16 [2048][1024]) + HT (fp16 [1024][2048])
// ---------------------------------------------------------------------------
__global__ __launch_bounds__(256)
void k_prep(const float* __restrict__ F1, const float* __restrict__ F2,
            _Float16* __restrict__ H1, _Float16* __restrict__ H2,
            _Float16* __restrict__ H1T, _Float16* __restrict__ H2T) {
  __shared__ _Float16 sT[64][72];
  const int bid = blockIdx.x;
  const int inp = bid >> 12;
  const int rem = bid & 4095;
  const int b = rem >> 9, rt = (rem >> 4) & 31, ct = rem & 15;
  const int r0 = rt * 64, c0 = ct * 64;

  const float* F = (inp ? F2 : F1) + (size_t)b * LDIM * DDIM;
  _Float16* H = (inp ? H2 : H1) + (size_t)b * LDIM * DDIM;
  _Float16* HT = (inp ? H2T : H1T) + (size_t)b * DDIM * LDIM;

  const int t = threadIdx.x;
  const int row = t >> 2, seg = (t & 3) * 16;
  {
    const float* src = F + (size_t)(r0 + row) * DDIM + c0 + seg;
    float4 v0 = *(const float4*)(src), v1 = *(const float4*)(src + 4);
    float4 v2 = *(const float4*)(src + 8), v3 = *(const float4*)(src + 12);
    f16x8 ha, hb;
#pragma unroll
    for (int j = 0; j < 4; ++j) {
      ha[j] = (_Float16)((&v0.x)[j]); ha[4 + j] = (_Float16)((&v1.x)[j]);
      hb[j] = (_Float16)((&v2.x)[j]); hb[4 + j] = (_Float16)((&v3.x)[j]);
    }
    _Float16* dst = H + (size_t)(r0 + row) * DDIM + c0 + seg;
    *(f16x8*)dst = ha;
    *(f16x8*)(dst + 8) = hb;
#pragma unroll
    for (int j = 0; j < 8; ++j) { sT[seg + j][row] = ha[j]; sT[seg + 8 + j][row] = hb[j]; }
  }
  __syncthreads();
  {
    const int cloc = t >> 2, rseg = (t & 3) * 16;
    _Float16* dst = HT + (size_t)(c0 + cloc) * LDIM + r0 + rseg;
    *(uint4*)dst = *(const uint4*)&sT[cloc][rseg];
    *(uint4*)(dst + 8) = *(const uint4*)&sT[cloc][rseg + 8];
  }
}

// ---------------------------------------------------------------------------
// k_qk: S = H1 H2^T (256x256 tiles, K=1024). Epilogue: per-(row, 256-block)
// partial softmax stats + P_unnorm fp16.
// ---------------------------------------------------------------------------
__global__ __launch_bounds__(512, 2)
void k_qk(const _Float16* __restrict__ H1, const _Float16* __restrict__ H2,
          _Float16* __restrict__ P, float2* __restrict__ partials) {
  __shared__ _Float16 sh[65536];
  const int tid = threadIdx.x;
  const int lane = tid & 63, w = tid >> 6;
  const int wm = w >> 2, wn = w & 3;
  const int l15 = lane & 15, g4 = lane >> 4;

  const int nwg = gridDim.x;  // 512
  const int orig = blockIdx.x;
  const int idx = (orig & 7) * (nwg >> 3) + (orig >> 3);
  const int b = idx >> 6, mt = (idx >> 3) & 7, ntb = idx & 7;
  const int m0 = mt << 8, n0 = ntb << 8;

  f32x4 acc[2][4][4];
#pragma unroll
  for (int i = 0; i < 2; ++i)
#pragma unroll
    for (int j = 0; j < 4; ++j)
#pragma unroll
      for (int k = 0; k < 4; ++k) acc[i][j][k] = (f32x4){0.f, 0.f, 0.f, 0.f};

  gemm8<1024, 16>(H1 + (size_t)b * LDIM * DDIM + (size_t)m0 * DDIM,
                  H2 + (size_t)b * LDIM * DDIM + (size_t)n0 * DDIM, sh, acc);

  float* sred = (float*)sh;        // [256][4] row-max per wn
  float* sredS = sred + 1024;      // [256][4] row-sum per wn
  __syncthreads();

#pragma unroll
  for (int mh = 0; mh < 2; ++mh)
#pragma unroll
    for (int mr = 0; mr < 4; ++mr)
#pragma unroll
      for (int r = 0; r < 4; ++r) {
        float v = fmaxf(fmaxf(acc[mh][mr][0][r], acc[mh][mr][1][r]),
                        fmaxf(acc[mh][mr][2][r], acc[mh][mr][3][r]));
        v = fmaxf(v, __shfl_xor(v, 1, 64));
        v = fmaxf(v, __shfl_xor(v, 2, 64));
        v = fmaxf(v, __shfl_xor(v, 4, 64));
        v = fmaxf(v, __shfl_xor(v, 8, 64));
        if (l15 == 0) sred[(wm * 128 + mh * 64 + mr * 16 + g4 * 4 + r) * 4 + wn] = v;
      }
  __syncthreads();

  _Float16* pOut = P + ((size_t)b << 22);
#pragma unroll
  for (int mh = 0; mh < 2; ++mh)
#pragma unroll
    for (int mr = 0; mr < 4; ++mr)
#pragma unroll
      for (int r = 0; r < 4; ++r) {
        const int row = wm * 128 + mh * 64 + mr * 16 + g4 * 4 + r;
        const float m = fmaxf(fmaxf(sred[row * 4], sred[row * 4 + 1]),
                              fmaxf(sred[row * 4 + 2], sred[row * 4 + 3]));
        float s = 0.f;
#pragma unroll
        for (int nr = 0; nr < 4; ++nr) {
          float p = __expf(acc[mh][mr][nr][r] - m);
          s += p;
          pOut[(size_t)(m0 + row) * LDIM + n0 + wn * 64 + nr * 16 + l15] = (_Float16)p;
        }
        s += __shfl_xor(s, 1, 64);
        s += __shfl_xor(s, 2, 64);
        s += __shfl_xor(s, 4, 64);
        s += __shfl_xor(s, 8, 64);
        if (l15 == 0) sredS[row * 4 + wn] = s;
      }
  __syncthreads();
  if (tid < 256) {
    const float m = fmaxf(fmaxf(sred[tid * 4], sred[tid * 4 + 1]),
                          fmaxf(sred[tid * 4 + 2], sred[tid * 4 + 3]));
    const float L = sredS[tid * 4] + sredS[tid * 4 + 1] + sredS[tid * 4 + 2] + sredS[tid * 4 + 3];
    partials[((size_t)(b * 8 + ntb) << 11) + m0 + tid] = make_float2(m, L);
  }
}

// ---------------------------------------------------------------------------
__global__ void k_merge(const float2* __restrict__ partials, float* __restrict__ factors) {
  const int t = blockIdx.x * 256 + threadIdx.x;
  if (t >= NB * LDIM) return;
  const int b = t >> 11, row = t & 2047;
  float2 p[8];
  float M = -1e30f;
#pragma unroll
  for (int i = 0; i < 8; ++i) {
    p[i] = partials[((size_t)(b * 8 + i) << 11) + row];
    M = fmaxf(M, p[i].x);
  }
  float L = 0.f;
#pragma unroll
  for (int i = 0; i < 8; ++i) L += p[i].y * __expf(p[i].x - M);
  const float inv = 1.0f / L;
#pragma unroll
  for (int i = 0; i < 8; ++i)
    factors[((size_t)(b * 8 + i) << 11) + row] = __expf(p[i].x - M) * inv;
}

// ---------------------------------------------------------------------------
// k_scale_t: P[m][n] *= f[m][n>>8] in place; also write PT[n][m] (rescaled).
// ---------------------------------------------------------------------------
__global__ __launch_bounds__(256)
void k_scale_t(_Float16* __restrict__ P, const float* __restrict__ factors,
               _Float16* __restrict__ PT) {
  __shared__ _Float16 sT[64][72];
  const int bid = blockIdx.x;
  const int b = bid >> 10, mt = (bid >> 5) & 31, nt = bid & 31;
  const int m0 = mt * 64, n0 = nt * 64;
  const int nblk = n0 >> 8;

  _Float16* p = P + ((size_t)b << 22);
  _Float16* pt = PT + ((size_t)b << 22);

  const int t = threadIdx.x;
  const int row = t >> 2, seg = (t & 3) * 16;
  {
    const float f = factors[((size_t)(b * 8 + nblk) << 11) + m0 + row];
    const _Float16 hf = (_Float16)f;
    _Float16* src = p + (size_t)(m0 + row) * LDIM + n0 + seg;
    f16x8 h0 = *(const f16x8*)src, h1 = *(const f16x8*)(src + 8);
#pragma unroll
    for (int j = 0; j < 8; ++j) { h0[j] *= hf; h1[j] *= hf; }
    *(f16x8*)src = h0;
    *(f16x8*)(src + 8) = h1;
#pragma unroll
    for (int j = 0; j < 8; ++j) { sT[seg + j][row] = h0[j]; sT[seg + 8 + j][row] = h1[j]; }
  }
  __syncthreads();
  {
    const int nloc = t >> 2, mseg = (t & 3) * 16;
    _Float16* dst = pt + (size_t)(n0 + nloc) * LDIM + m0 + mseg;
    *(uint4*)dst = *(const uint4*)&sT[nloc][mseg];
    *(uint4*)(dst + 8) = *(const uint4*)&sT[nloc][mseg + 8];
  }
}

// ---------------------------------------------------------------------------
// k_gemm: C[2048][1024] = A(2048 rows, K=2048) x B(1024 rows, K=2048)^T
// ---------------------------------------------------------------------------
__global__ __launch_bounds__(512, 2)
void k_gemm(const _Float16* __restrict__ A, const _Float16* __restrict__ B,
            float* __restrict__ C) {
  __shared__ _Float16 sh[65536];
  const int tid = threadIdx.x;
  const int lane = tid & 63, w = tid >> 6;
  const int wm = w >> 2, wn = w & 3;
  const int l15 = lane & 15, g4 = lane >> 4;

  const int nwg = gridDim.x;  // 256
  const int orig = blockIdx.x;
  const int idx = (orig & 7) * (nwg >> 3) + (orig >> 3);
  const int b = idx >> 5, mt = (idx >> 2) & 7, dt = idx & 3;
  const int m0 = mt << 8, d0 = dt << 8;

  f32x4 acc[2][4][4];
#pragma unroll
  for (int i = 0; i < 2; ++i)
#pragma unroll
    for (int j = 0; j < 4; ++j)
#pragma unroll
      for (int k = 0; k < 4; ++k) acc[i][j][k] = (f32x4){0.f, 0.f, 0.f, 0.f};

  gemm8<2048, 32>(A + ((size_t)b << 22) + (size_t)m0 * LDIM,
                  B + ((size_t)b << 21) + (size_t)d0 * LDIM, sh, acc);

  float* outp = C + (size_t)b * LDIM * DDIM;
#pragma unroll
  for (int mh = 0; mh < 2; ++mh)
#pragma unroll
    for (int mr = 0; mr < 4; ++mr)
#pragma unroll
      for (int nr = 0; nr < 4; ++nr)
#pragma unroll
        for (int r = 0; r < 4; ++r)
          outp[(size_t)(m0 + wm * 128 + mh * 64 + mr * 16 + g4 * 4 + r) * DDIM +
               d0 + wn * 64 + nr * 16 + l15] = acc[mh][mr][nr][r];
}

// ---------------------------------------------------------------------------
extern "C" void kernel_launch(void* const* d_in, const int* in_sizes, int n_in,
                              void* d_out, int out_size, void* d_ws, size_t ws_size,
                              hipStream_t stream) {
  const float* f1 = (const float*)d_in[0];
  const float* f2 = (const float*)d_in[1];
  float* out1 = (float*)d_out;
  float* out2 = out1 + (size_t)NB * LDIM * DDIM;

  char* ws = (char*)d_ws;
  _Float16* H1T = (_Float16*)(ws);                      // 32 MB
  _Float16* H2T = (_Float16*)(ws + 33554432ull);        // 32 MB
  _Float16* P   = (_Float16*)(ws + 67108864ull);        // 64 MB
  _Float16* PT  = (_Float16*)(ws + 134217728ull);       // 64 MB (overlaps H1,H2)
  _Float16* H1  = (_Float16*)(ws + 134217728ull);       // 32 MB (dead after k_qk)
  _Float16* H2  = (_Float16*)(ws + 167772160ull);       // 32 MB (dead after k_qk)
  float2* partials = (float2*)(ws + 201326592ull);      // 1 MB
  float* factors   = (float*)(ws + 203423744ull);       // 512 KB

  k_prep<<<dim3(8192), dim3(256), 0, stream>>>(f1, f2, H1, H2, H1T, H2T);
  k_qk<<<dim3(512), dim3(512), 0, stream>>>(H1, H2, P, partials);
  k_merge<<<dim3(64), dim3(256), 0, stream>>>(partials, factors);
  k_scale_t<<<dim3(8192), dim3(256), 0, stream>>>(P, factors, PT);
  k_gemm<<<dim3(256), dim3(512), 0, stream>>>(P, H2T, out1);
  k_gemm<<<dim3(256), dim3(512), 0, stream>>>(PT, H1T, out2);
}